// Round 1
// baseline (7919.382 us; speedup 1.0000x reference)
//
#include <hip/hip_runtime.h>
#include <math.h>

#define N_NODES 50000
#define N_EDGES 800000
#define F_IN    128
#define HID     256
#define BN_EPS  1e-5f

// ---------------------------------------------------------------- degrees
__global__ void deg_kernel(const int* __restrict__ dst, float* __restrict__ deg) {
    int e = blockIdx.x * blockDim.x + threadIdx.x;
    if (e < N_EDGES) atomicAdd(&deg[dst[e]], 1.0f);
}

__global__ void invdeg_kernel(float* __restrict__ deg) {
    int i = blockIdx.x * blockDim.x + threadIdx.x;
    if (i < N_NODES) deg[i] = 1.0f / fmaxf(deg[i], 1.0f);
}

// ---------------------------------------------------------------- scatter-add
// one thread per (edge, 4-feature group); float4 gather, 4 scalar atomics
template<int D>
__global__ void scatter_add_kernel(const float* __restrict__ x,
                                   const int* __restrict__ src,
                                   const int* __restrict__ dst,
                                   float* __restrict__ agg) {
    const int D4 = D / 4;
    int i = blockIdx.x * blockDim.x + threadIdx.x;
    if (i >= N_EDGES * D4) return;
    int e  = i / D4;             // D4 is power of two -> shift
    int f4 = (i % D4) * 4;
    int s = src[e], t = dst[e];
    const float4 v = *(const float4*)&x[(long)s * D + f4];
    float* p = &agg[(long)t * D + f4];
    atomicAdd(p + 0, v.x);
    atomicAdd(p + 1, v.y);
    atomicAdd(p + 2, v.z);
    atomicAdd(p + 3, v.w);
}

// ---------------------------------------------------------------- fused GEMM
// h[r][c] = sum_k (agg[r][k]*invdeg[r]) * Wn[k][c] + sum_k x[r][k] * Wr[k][c] + bn[c]
// 256 threads = 256 output cols; ROWS rows per block staged in LDS.
// Safe to call with h == agg (block reads only its own rows into LDS first).
template<int DIN, int ROWS>
__global__ __launch_bounds__(256) void gemm_kernel(
    const float* __restrict__ agg, const float* __restrict__ invdeg,
    const float* __restrict__ x,
    const float* __restrict__ Wn, const float* __restrict__ Wr,
    const float* __restrict__ bn, float* __restrict__ h) {
    __shared__ float a_s[ROWS][DIN];
    __shared__ float x_s[ROWS][DIN];
    const int tid = threadIdx.x;
    const int r0 = blockIdx.x * ROWS;

    for (int idx = tid; idx < ROWS * DIN; idx += 256) {
        int r = idx / DIN, k = idx % DIN;
        int row = r0 + r;
        float av = 0.f, xv = 0.f;
        if (row < N_NODES) {
            av = agg[(long)row * DIN + k] * invdeg[row];
            xv = x[(long)row * DIN + k];
        }
        a_s[r][k] = av;
        x_s[r][k] = xv;
    }
    __syncthreads();

    float acc[ROWS];
#pragma unroll
    for (int r = 0; r < ROWS; r++) acc[r] = 0.f;

    for (int k4 = 0; k4 < DIN; k4 += 4) {
        float w0 = Wn[(k4 + 0) * HID + tid];
        float w1 = Wn[(k4 + 1) * HID + tid];
        float w2 = Wn[(k4 + 2) * HID + tid];
        float w3 = Wn[(k4 + 3) * HID + tid];
#pragma unroll
        for (int r = 0; r < ROWS; r++) {
            float4 a = *(const float4*)&a_s[r][k4];
            acc[r] += a.x * w0 + a.y * w1 + a.z * w2 + a.w * w3;
        }
    }
    for (int k4 = 0; k4 < DIN; k4 += 4) {
        float w0 = Wr[(k4 + 0) * HID + tid];
        float w1 = Wr[(k4 + 1) * HID + tid];
        float w2 = Wr[(k4 + 2) * HID + tid];
        float w3 = Wr[(k4 + 3) * HID + tid];
#pragma unroll
        for (int r = 0; r < ROWS; r++) {
            float4 a = *(const float4*)&x_s[r][k4];
            acc[r] += a.x * w0 + a.y * w1 + a.z * w2 + a.w * w3;
        }
    }

    float bias = bn[tid];
#pragma unroll
    for (int r = 0; r < ROWS; r++) {
        int row = r0 + r;
        if (row < N_NODES) h[(long)row * HID + tid] = acc[r] + bias;
    }
}

// ---------------------------------------------------------------- BN stats
// s12[0:256] = column sums, s12[256:512] = column sums of squares
__global__ void bn_stats_kernel(const float* __restrict__ h, float* __restrict__ s12) {
    const int c = threadIdx.x;  // 256 threads = 256 cols
    float s = 0.f, ss = 0.f;
    for (int r = blockIdx.x; r < N_NODES; r += gridDim.x) {
        float v = h[(long)r * HID + c];
        s += v;
        ss += v * v;
    }
    atomicAdd(&s12[c], s);
    atomicAdd(&s12[HID + c], ss);
}

// ---------------------------------------------------------------- BN + ELU
__global__ void bn_elu_kernel(const float* __restrict__ h, const float* __restrict__ s12,
                              const float* __restrict__ g, const float* __restrict__ b,
                              float* __restrict__ out) {
    const int total4 = N_NODES * HID / 4;
    int i = blockIdx.x * blockDim.x + threadIdx.x;
    if (i >= total4) return;
    int c4 = (i % (HID / 4)) * 4;
    float4 v = *(const float4*)&h[(long)i * 4];
    float in[4] = {v.x, v.y, v.z, v.w};
    float o[4];
#pragma unroll
    for (int j = 0; j < 4; j++) {
        int c = c4 + j;
        float mu  = s12[c] * (1.0f / N_NODES);
        float var = s12[HID + c] * (1.0f / N_NODES) - mu * mu;
        var = fmaxf(var, 0.f);
        float inv = rsqrtf(var + BN_EPS);
        float t = (in[j] - mu) * inv * g[c] + b[c];
        o[j] = t > 0.f ? t : expm1f(t);
    }
    float4 ov = {o[0], o[1], o[2], o[3]};
    *(float4*)&out[(long)i * 4] = ov;
}

// ---------------------------------------------------------------- launch
extern "C" void kernel_launch(void* const* d_in, const int* in_sizes, int n_in,
                              void* d_out, int out_size, void* d_ws, size_t ws_size,
                              hipStream_t stream) {
    const float* x   = (const float*)d_in[0];
    const int*   ei  = (const int*)d_in[1];
    const int*   src = ei;
    const int*   dst = ei + N_EDGES;
    const float* Wn[3] = {(const float*)d_in[2],  (const float*)d_in[7],  (const float*)d_in[12]};
    const float* bn[3] = {(const float*)d_in[3],  (const float*)d_in[8],  (const float*)d_in[13]};
    const float* Wr[3] = {(const float*)d_in[4],  (const float*)d_in[9],  (const float*)d_in[14]};
    const float* g [3] = {(const float*)d_in[5],  (const float*)d_in[10], (const float*)d_in[15]};
    const float* b [3] = {(const float*)d_in[6],  (const float*)d_in[11], (const float*)d_in[16]};
    float* out = (float*)d_out;

    const size_t BIG = (size_t)N_NODES * HID * sizeof(float);  // 51.2 MB
    char* ws = (char*)d_ws;
    float* P0  = (float*)(ws);                 // buffer 0
    float* P1  = (float*)(ws + BIG);           // buffer 1
    float* deg = (float*)(ws + 2 * BIG);       // N floats (deg -> invdeg in place)
    float* s12 = (float*)(ws + 2 * BIG + ((size_t)N_NODES * 4 + 255) / 256 * 256);

    const int scatter_blocks0 = (N_EDGES * (F_IN / 4) + 255) / 256;
    const int scatter_blocks1 = (N_EDGES * (HID / 4) + 255) / 256;
    const int elu_blocks = (N_NODES * HID / 4 + 255) / 256;

    // degrees (shared across layers)
    hipMemsetAsync(deg, 0, N_NODES * sizeof(float), stream);
    deg_kernel<<<(N_EDGES + 255) / 256, 256, 0, stream>>>(dst, deg);
    invdeg_kernel<<<(N_NODES + 255) / 256, 256, 0, stream>>>(deg);

    // ---------------- layer 0: x[50000,128] -> P1
    hipMemsetAsync(P0, 0, (size_t)N_NODES * F_IN * sizeof(float), stream);
    scatter_add_kernel<F_IN><<<scatter_blocks0, 256, 0, stream>>>(x, src, dst, P0);
    gemm_kernel<F_IN, 16><<<N_NODES / 16, 256, 0, stream>>>(P0, deg, x, Wn[0], Wr[0], bn[0], P1);
    hipMemsetAsync(s12, 0, 2 * HID * sizeof(float), stream);
    bn_stats_kernel<<<256, 256, 0, stream>>>(P1, s12);
    bn_elu_kernel<<<elu_blocks, 256, 0, stream>>>(P1, s12, g[0], b[0], P1);

    // ---------------- layer 1: P1 -> P0 (gemm in-place over agg in P0)
    hipMemsetAsync(P0, 0, BIG, stream);
    scatter_add_kernel<HID><<<scatter_blocks1, 256, 0, stream>>>(P1, src, dst, P0);
    gemm_kernel<HID, 16><<<N_NODES / 16, 256, 0, stream>>>(P0, deg, P1, Wn[1], Wr[1], bn[1], P0);
    hipMemsetAsync(s12, 0, 2 * HID * sizeof(float), stream);
    bn_stats_kernel<<<256, 256, 0, stream>>>(P0, s12);
    bn_elu_kernel<<<elu_blocks, 256, 0, stream>>>(P0, s12, g[1], b[1], P0);

    // ---------------- layer 2: P0 -> out (agg in P1)
    hipMemsetAsync(P1, 0, BIG, stream);
    scatter_add_kernel<HID><<<scatter_blocks1, 256, 0, stream>>>(P0, src, dst, P1);
    gemm_kernel<HID, 16><<<N_NODES / 16, 256, 0, stream>>>(P1, deg, P0, Wn[2], Wr[2], bn[2], out);
    hipMemsetAsync(s12, 0, 2 * HID * sizeof(float), stream);
    bn_stats_kernel<<<256, 256, 0, stream>>>(out, s12);
    bn_elu_kernel<<<elu_blocks, 256, 0, stream>>>(out, s12, g[2], b[2], out);
}

// Round 2
// 1643.163 us; speedup vs baseline: 4.8196x; 4.8196x over previous
//
#include <hip/hip_runtime.h>
#include <math.h>

#define N_NODES 50000
#define N_EDGES 800000
#define F_IN    128
#define HID     256
#define BN_EPS  1e-5f

// ---------------------------------------------------------------- CSR build
__global__ void hist_kernel(const int* __restrict__ dst, int* __restrict__ deg) {
    int e = blockIdx.x * blockDim.x + threadIdx.x;
    if (e < N_EDGES) atomicAdd(&deg[dst[e]], 1);
}

// single-block exclusive scan of deg -> row_ptr (and cursor copy)
__global__ __launch_bounds__(1024) void scan_kernel(const int* __restrict__ deg,
                                                    int* __restrict__ row_ptr,
                                                    int* __restrict__ cursor) {
    __shared__ int smem[1024];
    __shared__ int running;
    if (threadIdx.x == 0) running = 0;
    __syncthreads();
    for (int base = 0; base < N_NODES; base += 1024) {
        int i = base + threadIdx.x;
        int v = (i < N_NODES) ? deg[i] : 0;
        smem[threadIdx.x] = v;
        __syncthreads();
        for (int off = 1; off < 1024; off <<= 1) {
            int t = 0;
            if (threadIdx.x >= off) t = smem[threadIdx.x - off];
            __syncthreads();
            if (threadIdx.x >= off) smem[threadIdx.x] += t;
            __syncthreads();
        }
        int incl = smem[threadIdx.x];
        int base_run = running;
        if (i < N_NODES) {
            int excl = base_run + incl - v;
            row_ptr[i] = excl;
            cursor[i]  = excl;
        }
        __syncthreads();
        if (threadIdx.x == 0) running = base_run + smem[1023];
        __syncthreads();
    }
    if (threadIdx.x == 0) row_ptr[N_NODES] = N_EDGES;
}

__global__ void fill_kernel(const int* __restrict__ src, const int* __restrict__ dst,
                            int* __restrict__ cursor, int* __restrict__ csr_src) {
    int e = blockIdx.x * blockDim.x + threadIdx.x;
    if (e >= N_EDGES) return;
    int pos = atomicAdd(&cursor[dst[e]], 1);
    csr_src[pos] = src[e];
}

// ---------------------------------------------------------------- gather-mean
// one 64-lane wave per destination node; lane owns D/64 contiguous floats.
// agg[n] = mean over in-edges of x[src]; deg-0 nodes -> 0.
template<int D>
__global__ __launch_bounds__(256) void gather_mean_kernel(
    const float* __restrict__ x, const int* __restrict__ row_ptr,
    const int* __restrict__ csr_src, float* __restrict__ agg) {
    constexpr int VPL = D / 64;                 // 2 (D=128) or 4 (D=256)
    int node = blockIdx.x * 4 + (threadIdx.x >> 6);
    int lane = threadIdx.x & 63;
    if (node >= N_NODES) return;
    int beg = row_ptr[node], end = row_ptr[node + 1];
    float acc[VPL];
#pragma unroll
    for (int j = 0; j < VPL; j++) acc[j] = 0.f;
    for (int e = beg; e < end; e++) {
        int s = csr_src[e];                     // wave-uniform
        const float* row = &x[(long)s * D + lane * VPL];
        if (VPL == 4) {
            float4 v = *(const float4*)row;
            acc[0] += v.x; acc[1] += v.y; acc[2] += v.z; acc[3] += v.w;
        } else {
            float2 v = *(const float2*)row;
            acc[0] += v.x; acc[1] += v.y;
        }
    }
    float inv = 1.0f / fmaxf((float)(end - beg), 1.0f);
    float* o = &agg[(long)node * D + lane * VPL];
    if (VPL == 4) {
        float4 ov = {acc[0] * inv, acc[1] * inv, acc[2] * inv, acc[3] * inv};
        *(float4*)o = ov;
    } else {
        float2 ov = {acc[0] * inv, acc[1] * inv};
        *(float2*)o = ov;
    }
}

// ---------------------------------------------------------------- fused GEMM
// h[r][c] = sum_k agg[r][k]*Wn[k][c] + sum_k x[r][k]*Wr[k][c] + bn[c]
// (agg already mean-normalized). Safe with h == agg.
template<int DIN, int ROWS>
__global__ __launch_bounds__(256) void gemm_kernel(
    const float* __restrict__ agg, const float* __restrict__ x,
    const float* __restrict__ Wn, const float* __restrict__ Wr,
    const float* __restrict__ bn, float* __restrict__ h) {
    __shared__ float a_s[ROWS][DIN];
    __shared__ float x_s[ROWS][DIN];
    const int tid = threadIdx.x;
    const int r0 = blockIdx.x * ROWS;

    for (int idx = tid; idx < ROWS * DIN; idx += 256) {
        int r = idx / DIN, k = idx % DIN;
        int row = r0 + r;
        float av = 0.f, xv = 0.f;
        if (row < N_NODES) {
            av = agg[(long)row * DIN + k];
            xv = x[(long)row * DIN + k];
        }
        a_s[r][k] = av;
        x_s[r][k] = xv;
    }
    __syncthreads();

    float acc[ROWS];
#pragma unroll
    for (int r = 0; r < ROWS; r++) acc[r] = 0.f;

    for (int k4 = 0; k4 < DIN; k4 += 4) {
        float w0 = Wn[(k4 + 0) * HID + tid];
        float w1 = Wn[(k4 + 1) * HID + tid];
        float w2 = Wn[(k4 + 2) * HID + tid];
        float w3 = Wn[(k4 + 3) * HID + tid];
#pragma unroll
        for (int r = 0; r < ROWS; r++) {
            float4 a = *(const float4*)&a_s[r][k4];
            acc[r] += a.x * w0 + a.y * w1 + a.z * w2 + a.w * w3;
        }
    }
    for (int k4 = 0; k4 < DIN; k4 += 4) {
        float w0 = Wr[(k4 + 0) * HID + tid];
        float w1 = Wr[(k4 + 1) * HID + tid];
        float w2 = Wr[(k4 + 2) * HID + tid];
        float w3 = Wr[(k4 + 3) * HID + tid];
#pragma unroll
        for (int r = 0; r < ROWS; r++) {
            float4 a = *(const float4*)&x_s[r][k4];
            acc[r] += a.x * w0 + a.y * w1 + a.z * w2 + a.w * w3;
        }
    }

    float bias = bn[tid];
#pragma unroll
    for (int r = 0; r < ROWS; r++) {
        int row = r0 + r;
        if (row < N_NODES) h[(long)row * HID + tid] = acc[r] + bias;
    }
}

// ---------------------------------------------------------------- BN stats
__global__ void bn_stats_kernel(const float* __restrict__ h, float* __restrict__ s12) {
    const int c = threadIdx.x;  // 256 threads = 256 cols
    float s = 0.f, ss = 0.f;
    for (int r = blockIdx.x; r < N_NODES; r += gridDim.x) {
        float v = h[(long)r * HID + c];
        s += v;
        ss += v * v;
    }
    atomicAdd(&s12[c], s);
    atomicAdd(&s12[HID + c], ss);
}

// ---------------------------------------------------------------- BN + ELU
__global__ void bn_elu_kernel(const float* __restrict__ h, const float* __restrict__ s12,
                              const float* __restrict__ g, const float* __restrict__ b,
                              float* __restrict__ out) {
    const int total4 = N_NODES * HID / 4;
    int i = blockIdx.x * blockDim.x + threadIdx.x;
    if (i >= total4) return;
    int c4 = (i % (HID / 4)) * 4;
    float4 v = *(const float4*)&h[(long)i * 4];
    float in[4] = {v.x, v.y, v.z, v.w};
    float o[4];
#pragma unroll
    for (int j = 0; j < 4; j++) {
        int c = c4 + j;
        float mu  = s12[c] * (1.0f / N_NODES);
        float var = s12[HID + c] * (1.0f / N_NODES) - mu * mu;
        var = fmaxf(var, 0.f);
        float inv = rsqrtf(var + BN_EPS);
        float t = (in[j] - mu) * inv * g[c] + b[c];
        o[j] = t > 0.f ? t : expm1f(t);
    }
    float4 ov = {o[0], o[1], o[2], o[3]};
    *(float4*)&out[(long)i * 4] = ov;
}

// ---------------------------------------------------------------- launch
extern "C" void kernel_launch(void* const* d_in, const int* in_sizes, int n_in,
                              void* d_out, int out_size, void* d_ws, size_t ws_size,
                              hipStream_t stream) {
    const float* x   = (const float*)d_in[0];
    const int*   ei  = (const int*)d_in[1];
    const int*   src = ei;
    const int*   dst = ei + N_EDGES;
    const float* Wn[3] = {(const float*)d_in[2],  (const float*)d_in[7],  (const float*)d_in[12]};
    const float* bn[3] = {(const float*)d_in[3],  (const float*)d_in[8],  (const float*)d_in[13]};
    const float* Wr[3] = {(const float*)d_in[4],  (const float*)d_in[9],  (const float*)d_in[14]};
    const float* g [3] = {(const float*)d_in[5],  (const float*)d_in[10], (const float*)d_in[15]};
    const float* b [3] = {(const float*)d_in[6],  (const float*)d_in[11], (const float*)d_in[16]};
    float* out = (float*)d_out;

    const size_t BIG = (size_t)N_NODES * HID * sizeof(float);  // 51.2 MB
    char* ws = (char*)d_ws;
    float* P0      = (float*)(ws);
    float* P1      = (float*)(ws + BIG);
    int*   row_ptr = (int*)  (ws + 2 * BIG);
    int*   cursor  = row_ptr + (N_NODES + 1);
    int*   deg_i   = cursor + N_NODES;
    int*   csr_src = deg_i + N_NODES;
    float* s12     = (float*)(csr_src + N_EDGES);

    const int eb = (N_EDGES + 255) / 256;
    const int gather_blocks = (N_NODES + 3) / 4;
    const int elu_blocks = (N_NODES * HID / 4 + 255) / 256;

    // ---------------- CSR build (once, reused by all 3 layers)
    hipMemsetAsync(deg_i, 0, N_NODES * sizeof(int), stream);
    hist_kernel<<<eb, 256, 0, stream>>>(dst, deg_i);
    scan_kernel<<<1, 1024, 0, stream>>>(deg_i, row_ptr, cursor);
    fill_kernel<<<eb, 256, 0, stream>>>(src, dst, cursor, csr_src);

    // ---------------- layer 0: x[50000,128] -> P1
    gather_mean_kernel<F_IN><<<gather_blocks, 256, 0, stream>>>(x, row_ptr, csr_src, P0);
    gemm_kernel<F_IN, 16><<<N_NODES / 16, 256, 0, stream>>>(P0, x, Wn[0], Wr[0], bn[0], P1);
    hipMemsetAsync(s12, 0, 2 * HID * sizeof(float), stream);
    bn_stats_kernel<<<256, 256, 0, stream>>>(P1, s12);
    bn_elu_kernel<<<elu_blocks, 256, 0, stream>>>(P1, s12, g[0], b[0], P1);

    // ---------------- layer 1: P1 -> P0 (gemm in-place over agg in P0)
    gather_mean_kernel<HID><<<gather_blocks, 256, 0, stream>>>(P1, row_ptr, csr_src, P0);
    gemm_kernel<HID, 16><<<N_NODES / 16, 256, 0, stream>>>(P0, P1, Wn[1], Wr[1], bn[1], P0);
    hipMemsetAsync(s12, 0, 2 * HID * sizeof(float), stream);
    bn_stats_kernel<<<256, 256, 0, stream>>>(P0, s12);
    bn_elu_kernel<<<elu_blocks, 256, 0, stream>>>(P0, s12, g[1], b[1], P0);

    // ---------------- layer 2: P0 -> out (agg in P1)
    gather_mean_kernel<HID><<<gather_blocks, 256, 0, stream>>>(P0, row_ptr, csr_src, P1);
    gemm_kernel<HID, 16><<<N_NODES / 16, 256, 0, stream>>>(P1, P0, Wn[2], Wr[2], bn[2], out);
    hipMemsetAsync(s12, 0, 2 * HID * sizeof(float), stream);
    bn_stats_kernel<<<256, 256, 0, stream>>>(out, s12);
    bn_elu_kernel<<<elu_blocks, 256, 0, stream>>>(out, s12, g[2], b[2], out);
}

// Round 4
// 986.542 us; speedup vs baseline: 8.0274x; 1.6656x over previous
//
#include <hip/hip_runtime.h>
#include <math.h>

#define N_NODES 50000
#define N_EDGES 800000
#define F_IN    128
#define HID     256
#define BN_EPS  1e-5f

typedef unsigned int uint;
typedef __attribute__((ext_vector_type(8))) short bf16x8;  // 8 bf16 = 4 VGPRs
typedef __attribute__((ext_vector_type(4))) float f32x4;

__device__ __forceinline__ float bf2f(unsigned short u) {
    return __uint_as_float((uint)u << 16);
}
__device__ __forceinline__ unsigned short f2bf(float f) {   // RTNE
    uint u = __float_as_uint(f);
    return (unsigned short)((u + 0x7FFFu + ((u >> 16) & 1u)) >> 16);
}

// ---------------------------------------------------------------- CSR build
__global__ void hist_kernel(const int* __restrict__ dst, int* __restrict__ deg) {
    int e = blockIdx.x * blockDim.x + threadIdx.x;
    if (e < N_EDGES) atomicAdd(&deg[dst[e]], 1);
}

__global__ __launch_bounds__(1024) void scan_kernel(const int* __restrict__ deg,
                                                    int* __restrict__ row_ptr,
                                                    int* __restrict__ cursor) {
    __shared__ int smem[1024];
    __shared__ int running;
    if (threadIdx.x == 0) running = 0;
    __syncthreads();
    for (int base = 0; base < N_NODES; base += 1024) {
        int i = base + threadIdx.x;
        int v = (i < N_NODES) ? deg[i] : 0;
        smem[threadIdx.x] = v;
        __syncthreads();
        for (int off = 1; off < 1024; off <<= 1) {
            int t = 0;
            if (threadIdx.x >= off) t = smem[threadIdx.x - off];
            __syncthreads();
            if (threadIdx.x >= off) smem[threadIdx.x] += t;
            __syncthreads();
        }
        int incl = smem[threadIdx.x];
        int base_run = running;
        if (i < N_NODES) {
            int excl = base_run + incl - v;
            row_ptr[i] = excl;
            cursor[i]  = excl;
        }
        __syncthreads();
        if (threadIdx.x == 0) running = base_run + smem[1023];
        __syncthreads();
    }
    if (threadIdx.x == 0) row_ptr[N_NODES] = N_EDGES;
}

__global__ void fill_kernel(const int* __restrict__ src, const int* __restrict__ dst,
                            int* __restrict__ cursor, int* __restrict__ csr_src) {
    int e = blockIdx.x * blockDim.x + threadIdx.x;
    if (e >= N_EDGES) return;
    int pos = atomicAdd(&cursor[dst[e]], 1);
    csr_src[pos] = src[e];
}

// ---------------------------------------------------------------- cast x -> bf16
__global__ void cast_bf16_kernel(const float* __restrict__ x, unsigned short* __restrict__ xb,
                                 int total4) {
    int i = blockIdx.x * blockDim.x + threadIdx.x;
    if (i >= total4) return;
    float4 v = *(const float4*)&x[(long)i * 4];
    unsigned short o[4] = {f2bf(v.x), f2bf(v.y), f2bf(v.z), f2bf(v.w)};
    *(uint2*)&xb[(long)i * 4] = *(const uint2*)o;
}

// ---------------------------------------------------------------- weight transpose
// WT[n][k] bf16, k < K1 from Wn[k][n], else Wr[k-K1][n]
__global__ void wt_kernel(const float* __restrict__ Wn, const float* __restrict__ Wr,
                          int K1, int KT, unsigned short* __restrict__ WT) {
    int k = blockIdx.x;     // 0..KT-1
    int n = threadIdx.x;    // 0..255
    float v = (k < K1) ? Wn[k * HID + n] : Wr[(k - K1) * HID + n];
    WT[(long)n * KT + k] = f2bf(v);
}

// ---------------------------------------------------------------- gather-mean (bf16)
// one 64-lane wave per destination node; agg = mean of x[src] rows
template<int D>
__global__ __launch_bounds__(256) void gather_mean_kernel(
    const unsigned short* __restrict__ x, const int* __restrict__ row_ptr,
    const int* __restrict__ csr_src, unsigned short* __restrict__ agg) {
    constexpr int VPL = D / 64;                 // 2 (D=128) or 4 (D=256)
    int node = blockIdx.x * 4 + (threadIdx.x >> 6);
    int lane = threadIdx.x & 63;
    if (node >= N_NODES) return;
    int beg = row_ptr[node], end = row_ptr[node + 1];
    float acc[VPL];
#pragma unroll
    for (int j = 0; j < VPL; j++) acc[j] = 0.f;
    for (int e = beg; e < end; e++) {
        int s = csr_src[e];                     // wave-uniform
        const unsigned short* row = &x[(long)s * D + lane * VPL];
        if constexpr (VPL == 4) {
            uint2 v = *(const uint2*)row;
            acc[0] += bf2f((unsigned short)(v.x & 0xFFFF));
            acc[1] += bf2f((unsigned short)(v.x >> 16));
            acc[2] += bf2f((unsigned short)(v.y & 0xFFFF));
            acc[3] += bf2f((unsigned short)(v.y >> 16));
        } else {
            uint v = *(const uint*)row;
            acc[0] += bf2f((unsigned short)(v & 0xFFFF));
            acc[1] += bf2f((unsigned short)(v >> 16));
        }
    }
    float inv = 1.0f / fmaxf((float)(end - beg), 1.0f);
    unsigned short* o = &agg[(long)node * D + lane * VPL];
    if constexpr (VPL == 4) {
        unsigned short ov[4] = {f2bf(acc[0] * inv), f2bf(acc[1] * inv),
                                f2bf(acc[2] * inv), f2bf(acc[3] * inv)};
        *(uint2*)o = *(const uint2*)ov;
    } else {
        unsigned short ov[2] = {f2bf(acc[0] * inv), f2bf(acc[1] * inv)};
        *(uint*)o = *(const uint*)ov;
    }
}

// ---------------------------------------------------------------- MFMA GEMM
// H[m][n] = sum_k A[m][k] * W[k][n] + bias[n],  A = [A1 | A2] bf16, W = WT[n][k] bf16
// block: 64 rows x 256 cols; 4 waves in 2x2; wave: 2 m-tiles x 8 n-tiles of 16x16
template<int K1, int K2>
__global__ __launch_bounds__(256) void mfma_gemm_kernel(
    const unsigned short* __restrict__ A1, const unsigned short* __restrict__ A2,
    const unsigned short* __restrict__ WT, const float* __restrict__ bias,
    unsigned short* __restrict__ Hout) {
    constexpr int KT  = K1 + K2;
    constexpr int BK  = 64;
    constexpr int LDP = BK + 8;                 // 72 bf16: +16B row shift kills conflicts
    __shared__ unsigned short As[64 * LDP];     // 9.0 KB
    __shared__ unsigned short Bs[256 * LDP];    // 36 KB

    const int tid  = threadIdx.x;
    const int wave = tid >> 6;
    const int lane = tid & 63;
    const int m16  = lane & 15;
    const int quad = lane >> 4;
    const int rw   = (wave & 1) * 32;
    const int cw   = (wave >> 1) * 128;
    const int r0   = blockIdx.x * 64;

    f32x4 acc[2][8];
#pragma unroll
    for (int mt = 0; mt < 2; mt++)
#pragma unroll
        for (int nt = 0; nt < 8; nt++) acc[mt][nt] = (f32x4){0.f, 0.f, 0.f, 0.f};

    for (int k0 = 0; k0 < KT; k0 += BK) {
        const unsigned short* Ab;
        int pitch, kk;
        if (k0 < K1) { Ab = A1; pitch = K1; kk = k0; }
        else         { Ab = A2; pitch = K2; kk = k0 - K1; }
        // stage A: 64 rows x 64 bf16; 16B chunks; 512 chunks / 256 thr = 2 iters
#pragma unroll
        for (int it = 0; it < 2; ++it) {
            int c = tid + it * 256;
            int row = c >> 3, ch = c & 7;
            int grow = min(r0 + row, N_NODES - 1);
            uint4 v = *(const uint4*)&Ab[(long)grow * pitch + kk + ch * 8];
            *(uint4*)&As[row * LDP + ch * 8] = v;
        }
        // stage B: 256 rows x 64 bf16; 2048 chunks -> 8 iters
#pragma unroll
        for (int it = 0; it < 8; ++it) {
            int c = tid + it * 256;
            int row = c >> 3, ch = c & 7;
            uint4 v = *(const uint4*)&WT[(long)row * KT + k0 + ch * 8];
            *(uint4*)&Bs[row * LDP + ch * 8] = v;
        }
        __syncthreads();
#pragma unroll
        for (int ks = 0; ks < 2; ++ks) {
            bf16x8 afrag[2], bfrag[8];
#pragma unroll
            for (int mt = 0; mt < 2; mt++)
                afrag[mt] = *(const bf16x8*)&As[(rw + mt * 16 + m16) * LDP + ks * 32 + quad * 8];
#pragma unroll
            for (int nt = 0; nt < 8; nt++)
                bfrag[nt] = *(const bf16x8*)&Bs[(cw + nt * 16 + m16) * LDP + ks * 32 + quad * 8];
#pragma unroll
            for (int mt = 0; mt < 2; mt++)
#pragma unroll
                for (int nt = 0; nt < 8; nt++)
                    acc[mt][nt] = __builtin_amdgcn_mfma_f32_16x16x32_bf16(
                        afrag[mt], bfrag[nt], acc[mt][nt], 0, 0, 0);
        }
        __syncthreads();
    }
    // epilogue: C/D layout col=lane&15, row=quad*4+reg
#pragma unroll
    for (int mt = 0; mt < 2; mt++) {
#pragma unroll
        for (int nt = 0; nt < 8; nt++) {
            int col = cw + nt * 16 + m16;
            float bv = bias[col];
#pragma unroll
            for (int reg = 0; reg < 4; reg++) {
                int row = r0 + rw + mt * 16 + quad * 4 + reg;
                if (row < N_NODES)
                    Hout[(long)row * HID + col] = f2bf(acc[mt][nt][reg] + bv);
            }
        }
    }
}

// ---------------------------------------------------------------- BN stats (bf16 in)
__global__ void bn_stats_kernel(const unsigned short* __restrict__ h, float* __restrict__ s12) {
    const int c = threadIdx.x;  // 256 threads = 256 cols
    float s = 0.f, ss = 0.f;
    for (int r = blockIdx.x; r < N_NODES; r += gridDim.x) {
        float v = bf2f(h[(long)r * HID + c]);
        s += v;
        ss += v * v;
    }
    atomicAdd(&s12[c], s);
    atomicAdd(&s12[HID + c], ss);
}

// ---------------------------------------------------------------- BN + ELU
// reads bf16 h; OUT32 ? writes fp32 : writes bf16
template<bool OUT32>
__global__ void bn_elu_kernel(const unsigned short* __restrict__ h, const float* __restrict__ s12,
                              const float* __restrict__ g, const float* __restrict__ b,
                              void* __restrict__ out) {
    const int total4 = N_NODES * HID / 4;
    int i = blockIdx.x * blockDim.x + threadIdx.x;
    if (i >= total4) return;
    int c4 = (i % (HID / 4)) * 4;
    uint2 v = *(const uint2*)&h[(long)i * 4];
    float in[4] = {bf2f((unsigned short)(v.x & 0xFFFF)), bf2f((unsigned short)(v.x >> 16)),
                   bf2f((unsigned short)(v.y & 0xFFFF)), bf2f((unsigned short)(v.y >> 16))};
    float o[4];
#pragma unroll
    for (int j = 0; j < 4; j++) {
        int c = c4 + j;
        float mu  = s12[c] * (1.0f / N_NODES);
        float var = s12[HID + c] * (1.0f / N_NODES) - mu * mu;
        var = fmaxf(var, 0.f);
        float inv = rsqrtf(var + BN_EPS);
        float t = (in[j] - mu) * inv * g[c] + b[c];
        o[j] = t > 0.f ? t : expm1f(t);
    }
    if (OUT32) {
        float4 ov = {o[0], o[1], o[2], o[3]};
        *(float4*)&((float*)out)[(long)i * 4] = ov;
    } else {
        unsigned short ov[4] = {f2bf(o[0]), f2bf(o[1]), f2bf(o[2]), f2bf(o[3])};
        *(uint2*)&((unsigned short*)out)[(long)i * 4] = *(const uint2*)ov;
    }
}

// ---------------------------------------------------------------- launch
extern "C" void kernel_launch(void* const* d_in, const int* in_sizes, int n_in,
                              void* d_out, int out_size, void* d_ws, size_t ws_size,
                              hipStream_t stream) {
    const float* x   = (const float*)d_in[0];
    const int*   ei  = (const int*)d_in[1];
    const int*   src = ei;
    const int*   dst = ei + N_EDGES;
    const float* Wn[3] = {(const float*)d_in[2],  (const float*)d_in[7],  (const float*)d_in[12]};
    const float* bn[3] = {(const float*)d_in[3],  (const float*)d_in[8],  (const float*)d_in[13]};
    const float* Wr[3] = {(const float*)d_in[4],  (const float*)d_in[9],  (const float*)d_in[14]};
    const float* g [3] = {(const float*)d_in[5],  (const float*)d_in[10], (const float*)d_in[15]};
    const float* b [3] = {(const float*)d_in[6],  (const float*)d_in[11], (const float*)d_in[16]};
    float* out = (float*)d_out;

    const size_t BF = (size_t)N_NODES * HID * 2;   // 25.6 MB (bf16 N x 256)
    char* ws = (char*)d_ws;
    unsigned short* B0  = (unsigned short*)(ws);                  // agg bf16
    unsigned short* B1  = (unsigned short*)(ws + BF);             // gemm out bf16
    unsigned short* B2  = (unsigned short*)(ws + 2 * BF);         // activations bf16
    unsigned short* XB  = (unsigned short*)(ws + 3 * BF);         // x bf16 [N,128] 12.8 MB
    char* ws2 = ws + 3 * BF + (size_t)N_NODES * F_IN * 2;
    unsigned short* WT0 = (unsigned short*)(ws2);                 // [256][256]
    unsigned short* WT1 = (unsigned short*)(ws2 + 256 * 256 * 2);
    unsigned short* WT2 = (unsigned short*)(ws2 + 256 * 256 * 2 + 256 * 512 * 2);
    char* ws3 = ws2 + 256 * 256 * 2 + 2 * (256 * 512 * 2);
    int*   row_ptr = (int*)ws3;
    int*   cursor  = row_ptr + (N_NODES + 1);
    int*   deg_i   = cursor + N_NODES;
    int*   csr_src = deg_i + N_NODES;
    float* s12     = (float*)(csr_src + N_EDGES);

    const int eb = (N_EDGES + 255) / 256;
    const int gather_blocks = (N_NODES + 3) / 4;
    const int elu_blocks = (N_NODES * HID / 4 + 255) / 256;
    const int gemm_blocks = (N_NODES + 63) / 64;

    // ---------------- one-time per call: CSR + bf16 weights/x
    hipMemsetAsync(deg_i, 0, N_NODES * sizeof(int), stream);
    hist_kernel<<<eb, 256, 0, stream>>>(dst, deg_i);
    scan_kernel<<<1, 1024, 0, stream>>>(deg_i, row_ptr, cursor);
    fill_kernel<<<eb, 256, 0, stream>>>(src, dst, cursor, csr_src);
    cast_bf16_kernel<<<(N_NODES * F_IN / 4 + 255) / 256, 256, 0, stream>>>(x, XB, N_NODES * F_IN / 4);
    wt_kernel<<<256, 256, 0, stream>>>(Wn[0], Wr[0], F_IN, 2 * F_IN, WT0);
    wt_kernel<<<512, 256, 0, stream>>>(Wn[1], Wr[1], HID, 2 * HID, WT1);
    wt_kernel<<<512, 256, 0, stream>>>(Wn[2], Wr[2], HID, 2 * HID, WT2);

    // ---------------- layer 0: XB[N,128] -> act B2
    gather_mean_kernel<F_IN><<<gather_blocks, 256, 0, stream>>>(XB, row_ptr, csr_src, B0);
    mfma_gemm_kernel<F_IN, F_IN><<<gemm_blocks, 256, 0, stream>>>(B0, XB, WT0, bn[0], B1);
    hipMemsetAsync(s12, 0, 2 * HID * sizeof(float), stream);
    bn_stats_kernel<<<256, 256, 0, stream>>>(B1, s12);
    bn_elu_kernel<false><<<elu_blocks, 256, 0, stream>>>(B1, s12, g[0], b[0], B2);

    // ---------------- layer 1: B2 -> act B2 (in-place safe: elu after gemm)
    gather_mean_kernel<HID><<<gather_blocks, 256, 0, stream>>>(B2, row_ptr, csr_src, B0);
    mfma_gemm_kernel<HID, HID><<<gemm_blocks, 256, 0, stream>>>(B0, B2, WT1, bn[1], B1);
    hipMemsetAsync(s12, 0, 2 * HID * sizeof(float), stream);
    bn_stats_kernel<<<256, 256, 0, stream>>>(B1, s12);
    bn_elu_kernel<false><<<elu_blocks, 256, 0, stream>>>(B1, s12, g[1], b[1], B2);

    // ---------------- layer 2: B2 -> out (fp32)
    gather_mean_kernel<HID><<<gather_blocks, 256, 0, stream>>>(B2, row_ptr, csr_src, B0);
    mfma_gemm_kernel<HID, HID><<<gemm_blocks, 256, 0, stream>>>(B0, B2, WT2, bn[2], B1);
    hipMemsetAsync(s12, 0, 2 * HID * sizeof(float), stream);
    bn_stats_kernel<<<256, 256, 0, stream>>>(B1, s12);
    bn_elu_kernel<true><<<elu_blocks, 256, 0, stream>>>(B1, s12, g[2], b[2], out);
}

// Round 5
// 851.657 us; speedup vs baseline: 9.2988x; 1.1584x over previous
//
#include <hip/hip_runtime.h>
#include <math.h>

#define N_NODES 50000
#define N_EDGES 800000
#define F_IN    128
#define HID     256
#define BN_EPS  1e-5f

typedef unsigned int uint;
typedef __attribute__((ext_vector_type(8))) short bf16x8;  // 8 bf16 = 4 VGPRs
typedef __attribute__((ext_vector_type(4))) float f32x4;

__device__ __forceinline__ float bf2f(unsigned short u) {
    return __uint_as_float((uint)u << 16);
}
__device__ __forceinline__ unsigned short f2bf(float f) {   // RTNE
    uint u = __float_as_uint(f);
    return (unsigned short)((u + 0x7FFFu + ((u >> 16) & 1u)) >> 16);
}

// ---------------------------------------------------------------- CSR build
__global__ void hist_kernel(const int* __restrict__ dst, int* __restrict__ deg) {
    int e = blockIdx.x * blockDim.x + threadIdx.x;
    if (e < N_EDGES) atomicAdd(&deg[dst[e]], 1);
}

// single-block chunked scan: thread t owns CHUNK contiguous elements
__global__ __launch_bounds__(1024) void scan_kernel(const int* __restrict__ deg,
                                                    int* __restrict__ row_ptr,
                                                    int* __restrict__ cursor) {
    __shared__ int ssum[1024];
    constexpr int T = 1024;
    constexpr int CHUNK = (N_NODES + T - 1) / T;   // 49
    const int t = threadIdx.x;
    const int begi = t * CHUNK;
    const int endi = min(begi + CHUNK, N_NODES);
    int loc = 0;
    for (int i = begi; i < endi; i++) loc += deg[i];
    ssum[t] = loc;
    __syncthreads();
    for (int off = 1; off < T; off <<= 1) {
        int v = (t >= off) ? ssum[t - off] : 0;
        __syncthreads();
        ssum[t] += v;
        __syncthreads();
    }
    int run = ssum[t] - loc;                        // exclusive prefix of chunk
    for (int i = begi; i < endi; i++) {
        row_ptr[i] = run;
        cursor[i]  = run;
        run += deg[i];
    }
    if (t == 0) row_ptr[N_NODES] = N_EDGES;
}

__global__ void fill_kernel(const int* __restrict__ src, const int* __restrict__ dst,
                            int* __restrict__ cursor, int* __restrict__ csr_src) {
    int e = blockIdx.x * blockDim.x + threadIdx.x;
    if (e >= N_EDGES) return;
    int pos = atomicAdd(&cursor[dst[e]], 1);
    csr_src[pos] = src[e];
}

// ---------------------------------------------------------------- cast x -> bf16
__global__ void cast_bf16_kernel(const float* __restrict__ x, unsigned short* __restrict__ xb,
                                 int total4) {
    int i = blockIdx.x * blockDim.x + threadIdx.x;
    if (i >= total4) return;
    float4 v = *(const float4*)&x[(long)i * 4];
    unsigned short o[4] = {f2bf(v.x), f2bf(v.y), f2bf(v.z), f2bf(v.w)};
    *(uint2*)&xb[(long)i * 4] = *(const uint2*)o;
}

// ---------------------------------------------------------------- weight transpose
// WT[n][k] bf16, k < K1 from Wn[k][n], else Wr[k-K1][n]
__global__ void wt_kernel(const float* __restrict__ Wn, const float* __restrict__ Wr,
                          int K1, int KT, unsigned short* __restrict__ WT) {
    int k = blockIdx.x;     // 0..KT-1
    int n = threadIdx.x;    // 0..255
    float v = (k < K1) ? Wn[k * HID + n] : Wr[(k - K1) * HID + n];
    WT[(long)n * KT + k] = f2bf(v);
}

// ---------------------------------------------------------------- gather-mean (bf16)
// one 64-lane wave per destination node; edge loop unrolled x2 for MLP
template<int D>
__global__ __launch_bounds__(256) void gather_mean_kernel(
    const unsigned short* __restrict__ x, const int* __restrict__ row_ptr,
    const int* __restrict__ csr_src, unsigned short* __restrict__ agg) {
    constexpr int VPL = D / 64;                 // 2 (D=128) or 4 (D=256)
    int node = blockIdx.x * 4 + (threadIdx.x >> 6);
    int lane = threadIdx.x & 63;
    if (node >= N_NODES) return;
    int beg = row_ptr[node], end = row_ptr[node + 1];
    float acc[VPL];
#pragma unroll
    for (int j = 0; j < VPL; j++) acc[j] = 0.f;
    int e = beg;
    for (; e + 2 <= end; e += 2) {
        int s0 = csr_src[e], s1 = csr_src[e + 1];
        const unsigned short* r0 = &x[(long)s0 * D + lane * VPL];
        const unsigned short* r1 = &x[(long)s1 * D + lane * VPL];
        if constexpr (VPL == 4) {
            uint2 v0 = *(const uint2*)r0;
            uint2 v1 = *(const uint2*)r1;
            acc[0] += bf2f((unsigned short)(v0.x & 0xFFFF)) + bf2f((unsigned short)(v1.x & 0xFFFF));
            acc[1] += bf2f((unsigned short)(v0.x >> 16))    + bf2f((unsigned short)(v1.x >> 16));
            acc[2] += bf2f((unsigned short)(v0.y & 0xFFFF)) + bf2f((unsigned short)(v1.y & 0xFFFF));
            acc[3] += bf2f((unsigned short)(v0.y >> 16))    + bf2f((unsigned short)(v1.y >> 16));
        } else {
            uint v0 = *(const uint*)r0;
            uint v1 = *(const uint*)r1;
            acc[0] += bf2f((unsigned short)(v0 & 0xFFFF)) + bf2f((unsigned short)(v1 & 0xFFFF));
            acc[1] += bf2f((unsigned short)(v0 >> 16))    + bf2f((unsigned short)(v1 >> 16));
        }
    }
    if (e < end) {
        int s0 = csr_src[e];
        const unsigned short* r0 = &x[(long)s0 * D + lane * VPL];
        if constexpr (VPL == 4) {
            uint2 v0 = *(const uint2*)r0;
            acc[0] += bf2f((unsigned short)(v0.x & 0xFFFF));
            acc[1] += bf2f((unsigned short)(v0.x >> 16));
            acc[2] += bf2f((unsigned short)(v0.y & 0xFFFF));
            acc[3] += bf2f((unsigned short)(v0.y >> 16));
        } else {
            uint v0 = *(const uint*)r0;
            acc[0] += bf2f((unsigned short)(v0 & 0xFFFF));
            acc[1] += bf2f((unsigned short)(v0 >> 16));
        }
    }
    float inv = 1.0f / fmaxf((float)(end - beg), 1.0f);
    unsigned short* o = &agg[(long)node * D + lane * VPL];
    if constexpr (VPL == 4) {
        unsigned short ov[4] = {f2bf(acc[0] * inv), f2bf(acc[1] * inv),
                                f2bf(acc[2] * inv), f2bf(acc[3] * inv)};
        *(uint2*)o = *(const uint2*)ov;
    } else {
        unsigned short ov[2] = {f2bf(acc[0] * inv), f2bf(acc[1] * inv)};
        *(uint*)o = *(const uint*)ov;
    }
}

// ---------------------------------------------------------------- MFMA GEMM + BN stats
// H[m][n] = sum_k A[m][k] * W[k][n] + bias[n];  also accumulates per-column
// sum/sumsq of h into s12[0:256]/s12[256:512] (block LDS reduce -> global atomic).
template<int K1, int K2>
__global__ __launch_bounds__(256) void mfma_gemm_kernel(
    const unsigned short* __restrict__ A1, const unsigned short* __restrict__ A2,
    const unsigned short* __restrict__ WT, const float* __restrict__ bias,
    unsigned short* __restrict__ Hout, float* __restrict__ s12) {
    constexpr int KT  = K1 + K2;
    constexpr int BK  = 64;
    constexpr int LDP = BK + 8;                 // 72 bf16: +16B row shift kills conflicts
    __shared__ unsigned short As[64 * LDP];     // 9.0 KB
    __shared__ unsigned short Bs[256 * LDP];    // 36 KB
    __shared__ float cs[256];                   // 1 KB
    __shared__ float cq[256];                   // 1 KB

    const int tid  = threadIdx.x;
    const int wave = tid >> 6;
    const int lane = tid & 63;
    const int m16  = lane & 15;
    const int quad = lane >> 4;
    const int rw   = (wave & 1) * 32;
    const int cw   = (wave >> 1) * 128;
    const int r0   = blockIdx.x * 64;

    if (tid < 256) { cs[tid] = 0.f; cq[tid] = 0.f; }

    f32x4 acc[2][8];
#pragma unroll
    for (int mt = 0; mt < 2; mt++)
#pragma unroll
        for (int nt = 0; nt < 8; nt++) acc[mt][nt] = (f32x4){0.f, 0.f, 0.f, 0.f};

    for (int k0 = 0; k0 < KT; k0 += BK) {
        const unsigned short* Ab;
        int pitch, kk;
        if (k0 < K1) { Ab = A1; pitch = K1; kk = k0; }
        else         { Ab = A2; pitch = K2; kk = k0 - K1; }
        // stage A: 64 rows x 64 bf16; 16B chunks; 512 chunks / 256 thr = 2 iters
#pragma unroll
        for (int it = 0; it < 2; ++it) {
            int c = tid + it * 256;
            int row = c >> 3, ch = c & 7;
            int grow = min(r0 + row, N_NODES - 1);
            uint4 v = *(const uint4*)&Ab[(long)grow * pitch + kk + ch * 8];
            *(uint4*)&As[row * LDP + ch * 8] = v;
        }
        // stage B: 256 rows x 64 bf16; 2048 chunks -> 8 iters
#pragma unroll
        for (int it = 0; it < 8; ++it) {
            int c = tid + it * 256;
            int row = c >> 3, ch = c & 7;
            uint4 v = *(const uint4*)&WT[(long)row * KT + k0 + ch * 8];
            *(uint4*)&Bs[row * LDP + ch * 8] = v;
        }
        __syncthreads();
#pragma unroll
        for (int ks = 0; ks < 2; ++ks) {
            bf16x8 afrag[2], bfrag[8];
#pragma unroll
            for (int mt = 0; mt < 2; mt++)
                afrag[mt] = *(const bf16x8*)&As[(rw + mt * 16 + m16) * LDP + ks * 32 + quad * 8];
#pragma unroll
            for (int nt = 0; nt < 8; nt++)
                bfrag[nt] = *(const bf16x8*)&Bs[(cw + nt * 16 + m16) * LDP + ks * 32 + quad * 8];
#pragma unroll
            for (int mt = 0; mt < 2; mt++)
#pragma unroll
                for (int nt = 0; nt < 8; nt++)
                    acc[mt][nt] = __builtin_amdgcn_mfma_f32_16x16x32_bf16(
                        afrag[mt], bfrag[nt], acc[mt][nt], 0, 0, 0);
        }
        __syncthreads();
    }
    // epilogue: C/D layout col=lane&15, row=quad*4+reg; fused column stats
#pragma unroll
    for (int nt = 0; nt < 8; nt++) {
        int col = cw + nt * 16 + m16;
        float bv = bias[col];
        float s = 0.f, q = 0.f;
#pragma unroll
        for (int mt = 0; mt < 2; mt++) {
#pragma unroll
            for (int reg = 0; reg < 4; reg++) {
                int row = r0 + rw + mt * 16 + quad * 4 + reg;
                float v = acc[mt][nt][reg] + bv;
                if (row < N_NODES) {
                    Hout[(long)row * HID + col] = f2bf(v);
                    s += v;
                    q += v * v;
                }
            }
        }
        atomicAdd(&cs[col], s);
        atomicAdd(&cq[col], q);
    }
    __syncthreads();
    if (tid < 256) {
        atomicAdd(&s12[tid], cs[tid]);
        atomicAdd(&s12[HID + tid], cq[tid]);
    }
}

// ---------------------------------------------------------------- BN + ELU
// reads bf16 h; OUT32 ? writes fp32 : writes bf16
template<bool OUT32>
__global__ void bn_elu_kernel(const unsigned short* __restrict__ h, const float* __restrict__ s12,
                              const float* __restrict__ g, const float* __restrict__ b,
                              void* __restrict__ out) {
    const int total4 = N_NODES * HID / 4;
    int i = blockIdx.x * blockDim.x + threadIdx.x;
    if (i >= total4) return;
    int c4 = (i % (HID / 4)) * 4;
    uint2 v = *(const uint2*)&h[(long)i * 4];
    float in[4] = {bf2f((unsigned short)(v.x & 0xFFFF)), bf2f((unsigned short)(v.x >> 16)),
                   bf2f((unsigned short)(v.y & 0xFFFF)), bf2f((unsigned short)(v.y >> 16))};
    float o[4];
#pragma unroll
    for (int j = 0; j < 4; j++) {
        int c = c4 + j;
        float mu  = s12[c] * (1.0f / N_NODES);
        float var = s12[HID + c] * (1.0f / N_NODES) - mu * mu;
        var = fmaxf(var, 0.f);
        float inv = rsqrtf(var + BN_EPS);
        float t = (in[j] - mu) * inv * g[c] + b[c];
        o[j] = t > 0.f ? t : expm1f(t);
    }
    if (OUT32) {
        float4 ov = {o[0], o[1], o[2], o[3]};
        *(float4*)&((float*)out)[(long)i * 4] = ov;
    } else {
        unsigned short ov[4] = {f2bf(o[0]), f2bf(o[1]), f2bf(o[2]), f2bf(o[3])};
        *(uint2*)&((unsigned short*)out)[(long)i * 4] = *(const uint2*)ov;
    }
}

// ---------------------------------------------------------------- launch
extern "C" void kernel_launch(void* const* d_in, const int* in_sizes, int n_in,
                              void* d_out, int out_size, void* d_ws, size_t ws_size,
                              hipStream_t stream) {
    const float* x   = (const float*)d_in[0];
    const int*   ei  = (const int*)d_in[1];
    const int*   src = ei;
    const int*   dst = ei + N_EDGES;
    const float* Wn[3] = {(const float*)d_in[2],  (const float*)d_in[7],  (const float*)d_in[12]};
    const float* bn[3] = {(const float*)d_in[3],  (const float*)d_in[8],  (const float*)d_in[13]};
    const float* Wr[3] = {(const float*)d_in[4],  (const float*)d_in[9],  (const float*)d_in[14]};
    const float* g [3] = {(const float*)d_in[5],  (const float*)d_in[10], (const float*)d_in[15]};
    const float* b [3] = {(const float*)d_in[6],  (const float*)d_in[11], (const float*)d_in[16]};
    float* out = (float*)d_out;

    const size_t BF = (size_t)N_NODES * HID * 2;   // 25.6 MB (bf16 N x 256)
    char* ws = (char*)d_ws;
    unsigned short* B0  = (unsigned short*)(ws);                  // agg bf16
    unsigned short* B1  = (unsigned short*)(ws + BF);             // gemm out bf16
    unsigned short* B2  = (unsigned short*)(ws + 2 * BF);         // activations bf16
    unsigned short* XB  = (unsigned short*)(ws + 3 * BF);         // x bf16 [N,128] 12.8 MB
    char* ws2 = ws + 3 * BF + (size_t)N_NODES * F_IN * 2;
    unsigned short* WT0 = (unsigned short*)(ws2);                 // [256][256]
    unsigned short* WT1 = (unsigned short*)(ws2 + 256 * 256 * 2);
    unsigned short* WT2 = (unsigned short*)(ws2 + 256 * 256 * 2 + 256 * 512 * 2);
    char* ws3 = ws2 + 256 * 256 * 2 + 2 * (256 * 512 * 2);
    int*   row_ptr = (int*)ws3;
    int*   cursor  = row_ptr + (N_NODES + 1);
    int*   deg_i   = cursor + N_NODES;
    int*   csr_src = deg_i + N_NODES;
    float* s12     = (float*)(csr_src + N_EDGES);

    const int eb = (N_EDGES + 255) / 256;
    const int gather_blocks = (N_NODES + 3) / 4;
    const int elu_blocks = (N_NODES * HID / 4 + 255) / 256;
    const int gemm_blocks = (N_NODES + 63) / 64;

    // ---------------- one-time per call: CSR + bf16 weights/x
    hipMemsetAsync(deg_i, 0, N_NODES * sizeof(int), stream);
    hist_kernel<<<eb, 256, 0, stream>>>(dst, deg_i);
    scan_kernel<<<1, 1024, 0, stream>>>(deg_i, row_ptr, cursor);
    fill_kernel<<<eb, 256, 0, stream>>>(src, dst, cursor, csr_src);
    cast_bf16_kernel<<<(N_NODES * F_IN / 4 + 255) / 256, 256, 0, stream>>>(x, XB, N_NODES * F_IN / 4);
    wt_kernel<<<256, 256, 0, stream>>>(Wn[0], Wr[0], F_IN, 2 * F_IN, WT0);
    wt_kernel<<<512, 256, 0, stream>>>(Wn[1], Wr[1], HID, 2 * HID, WT1);
    wt_kernel<<<512, 256, 0, stream>>>(Wn[2], Wr[2], HID, 2 * HID, WT2);

    // ---------------- layer 0: XB[N,128] -> act B2
    gather_mean_kernel<F_IN><<<gather_blocks, 256, 0, stream>>>(XB, row_ptr, csr_src, B0);
    hipMemsetAsync(s12, 0, 2 * HID * sizeof(float), stream);
    mfma_gemm_kernel<F_IN, F_IN><<<gemm_blocks, 256, 0, stream>>>(B0, XB, WT0, bn[0], B1, s12);
    bn_elu_kernel<false><<<elu_blocks, 256, 0, stream>>>(B1, s12, g[0], b[0], B2);

    // ---------------- layer 1: B2 -> act B2
    gather_mean_kernel<HID><<<gather_blocks, 256, 0, stream>>>(B2, row_ptr, csr_src, B0);
    hipMemsetAsync(s12, 0, 2 * HID * sizeof(float), stream);
    mfma_gemm_kernel<HID, HID><<<gemm_blocks, 256, 0, stream>>>(B0, B2, WT1, bn[1], B1, s12);
    bn_elu_kernel<false><<<elu_blocks, 256, 0, stream>>>(B1, s12, g[1], b[1], B2);

    // ---------------- layer 2: B2 -> out (fp32)
    gather_mean_kernel<HID><<<gather_blocks, 256, 0, stream>>>(B2, row_ptr, csr_src, B0);
    hipMemsetAsync(s12, 0, 2 * HID * sizeof(float), stream);
    mfma_gemm_kernel<HID, HID><<<gemm_blocks, 256, 0, stream>>>(B0, B2, WT2, bn[2], B1, s12);
    bn_elu_kernel<true><<<elu_blocks, 256, 0, stream>>>(B1, s12, g[2], b[2], out);
}

// Round 6
// 722.762 us; speedup vs baseline: 10.9571x; 1.1783x over previous
//
#include <hip/hip_runtime.h>
#include <math.h>

#define N_NODES 50000
#define N_EDGES 800000
#define F_IN    128
#define HID     256
#define BN_EPS  1e-5f
#define SCAN_BLOCKS ((N_NODES + 255) / 256)   // 196

typedef unsigned int uint;
typedef __attribute__((ext_vector_type(8))) short bf16x8;  // 8 bf16 = 4 VGPRs
typedef __attribute__((ext_vector_type(4))) float f32x4;

__device__ __forceinline__ float bf2f(unsigned short u) {
    return __uint_as_float((uint)u << 16);
}
__device__ __forceinline__ unsigned short f2bf(float f) {   // RTNE
    uint u = __float_as_uint(f);
    return (unsigned short)((u + 0x7FFFu + ((u >> 16) & 1u)) >> 16);
}

// ---------------------------------------------------------------- CSR build
__global__ void hist_kernel(const int* __restrict__ dst, int* __restrict__ deg) {
    int e = blockIdx.x * blockDim.x + threadIdx.x;
    if (e < N_EDGES) atomicAdd(&deg[dst[e]], 1);
}

// pass 1: per-tile inclusive scan; write tile-local exclusive + tile totals
__global__ __launch_bounds__(256) void scan1_kernel(const int* __restrict__ deg,
                                                    int* __restrict__ row_ptr,
                                                    int* __restrict__ partials) {
    __shared__ int sm[256];
    int i = blockIdx.x * 256 + threadIdx.x;
    int v = (i < N_NODES) ? deg[i] : 0;
    sm[threadIdx.x] = v;
    __syncthreads();
    for (int off = 1; off < 256; off <<= 1) {
        int t = (threadIdx.x >= off) ? sm[threadIdx.x - off] : 0;
        __syncthreads();
        sm[threadIdx.x] += t;
        __syncthreads();
    }
    if (i < N_NODES) row_ptr[i] = sm[threadIdx.x] - v;   // tile-local exclusive
    if (threadIdx.x == 255) partials[blockIdx.x] = sm[255];
}

// pass 2: scan the tile totals (196 values) -> exclusive bases, in place
__global__ __launch_bounds__(256) void scan2_kernel(int* __restrict__ partials) {
    __shared__ int sm[256];
    int t = threadIdx.x;
    int v = (t < SCAN_BLOCKS) ? partials[t] : 0;
    sm[t] = v;
    __syncthreads();
    for (int off = 1; off < 256; off <<= 1) {
        int p = (t >= off) ? sm[t - off] : 0;
        __syncthreads();
        sm[t] += p;
        __syncthreads();
    }
    if (t < SCAN_BLOCKS) partials[t] = sm[t] - v;        // exclusive base
}

// pass 3: add block base, emit cursor copy
__global__ __launch_bounds__(256) void scan3_kernel(int* __restrict__ row_ptr,
                                                    int* __restrict__ cursor,
                                                    const int* __restrict__ partials) {
    int i = blockIdx.x * 256 + threadIdx.x;
    if (i < N_NODES) {
        int v = row_ptr[i] + partials[blockIdx.x];
        row_ptr[i] = v;
        cursor[i]  = v;
    }
    if (i == 0) row_ptr[N_NODES] = N_EDGES;
}

__global__ void fill_kernel(const int* __restrict__ src, const int* __restrict__ dst,
                            int* __restrict__ cursor, int* __restrict__ csr_src) {
    int e = blockIdx.x * blockDim.x + threadIdx.x;
    if (e >= N_EDGES) return;
    int pos = atomicAdd(&cursor[dst[e]], 1);
    csr_src[pos] = src[e];
}

// ---------------------------------------------------------------- cast x -> bf16
__global__ void cast_bf16_kernel(const float* __restrict__ x, unsigned short* __restrict__ xb,
                                 int total4) {
    int i = blockIdx.x * blockDim.x + threadIdx.x;
    if (i >= total4) return;
    float4 v = *(const float4*)&x[(long)i * 4];
    unsigned short o[4] = {f2bf(v.x), f2bf(v.y), f2bf(v.z), f2bf(v.w)};
    *(uint2*)&xb[(long)i * 4] = *(const uint2*)o;
}

// ---------------------------------------------------------------- weight transpose
__global__ void wt_kernel(const float* __restrict__ Wn, const float* __restrict__ Wr,
                          int K1, int KT, unsigned short* __restrict__ WT) {
    int k = blockIdx.x;     // 0..KT-1
    int n = threadIdx.x;    // 0..255
    float v = (k < K1) ? Wn[k * HID + n] : Wr[(k - K1) * HID + n];
    WT[(long)n * KT + k] = f2bf(v);
}

// ---------------------------------------------------------------- gather-mean (bf16)
// one 64-lane wave per destination node; edge loop unrolled x4 for MLP
template<int D>
__global__ __launch_bounds__(256) void gather_mean_kernel(
    const unsigned short* __restrict__ x, const int* __restrict__ row_ptr,
    const int* __restrict__ csr_src, unsigned short* __restrict__ agg) {
    constexpr int VPL = D / 64;                 // 2 (D=128) or 4 (D=256)
    int node = blockIdx.x * 4 + (threadIdx.x >> 6);
    int lane = threadIdx.x & 63;
    if (node >= N_NODES) return;
    int beg = row_ptr[node], end = row_ptr[node + 1];
    float acc[VPL];
#pragma unroll
    for (int j = 0; j < VPL; j++) acc[j] = 0.f;
    int e = beg;
    for (; e + 4 <= end; e += 4) {
        int s0 = csr_src[e], s1 = csr_src[e + 1], s2 = csr_src[e + 2], s3 = csr_src[e + 3];
        if constexpr (VPL == 4) {
            uint2 v0 = *(const uint2*)&x[(long)s0 * D + lane * 4];
            uint2 v1 = *(const uint2*)&x[(long)s1 * D + lane * 4];
            uint2 v2 = *(const uint2*)&x[(long)s2 * D + lane * 4];
            uint2 v3 = *(const uint2*)&x[(long)s3 * D + lane * 4];
            acc[0] += (bf2f((unsigned short)(v0.x & 0xFFFF)) + bf2f((unsigned short)(v1.x & 0xFFFF)))
                    + (bf2f((unsigned short)(v2.x & 0xFFFF)) + bf2f((unsigned short)(v3.x & 0xFFFF)));
            acc[1] += (bf2f((unsigned short)(v0.x >> 16))    + bf2f((unsigned short)(v1.x >> 16)))
                    + (bf2f((unsigned short)(v2.x >> 16))    + bf2f((unsigned short)(v3.x >> 16)));
            acc[2] += (bf2f((unsigned short)(v0.y & 0xFFFF)) + bf2f((unsigned short)(v1.y & 0xFFFF)))
                    + (bf2f((unsigned short)(v2.y & 0xFFFF)) + bf2f((unsigned short)(v3.y & 0xFFFF)));
            acc[3] += (bf2f((unsigned short)(v0.y >> 16))    + bf2f((unsigned short)(v1.y >> 16)))
                    + (bf2f((unsigned short)(v2.y >> 16))    + bf2f((unsigned short)(v3.y >> 16)));
        } else {
            uint v0 = *(const uint*)&x[(long)s0 * D + lane * 2];
            uint v1 = *(const uint*)&x[(long)s1 * D + lane * 2];
            uint v2 = *(const uint*)&x[(long)s2 * D + lane * 2];
            uint v3 = *(const uint*)&x[(long)s3 * D + lane * 2];
            acc[0] += (bf2f((unsigned short)(v0 & 0xFFFF)) + bf2f((unsigned short)(v1 & 0xFFFF)))
                    + (bf2f((unsigned short)(v2 & 0xFFFF)) + bf2f((unsigned short)(v3 & 0xFFFF)));
            acc[1] += (bf2f((unsigned short)(v0 >> 16))    + bf2f((unsigned short)(v1 >> 16)))
                    + (bf2f((unsigned short)(v2 >> 16))    + bf2f((unsigned short)(v3 >> 16)));
        }
    }
    for (; e < end; e++) {
        int s0 = csr_src[e];
        if constexpr (VPL == 4) {
            uint2 v0 = *(const uint2*)&x[(long)s0 * D + lane * 4];
            acc[0] += bf2f((unsigned short)(v0.x & 0xFFFF));
            acc[1] += bf2f((unsigned short)(v0.x >> 16));
            acc[2] += bf2f((unsigned short)(v0.y & 0xFFFF));
            acc[3] += bf2f((unsigned short)(v0.y >> 16));
        } else {
            uint v0 = *(const uint*)&x[(long)s0 * D + lane * 2];
            acc[0] += bf2f((unsigned short)(v0 & 0xFFFF));
            acc[1] += bf2f((unsigned short)(v0 >> 16));
        }
    }
    float inv = 1.0f / fmaxf((float)(end - beg), 1.0f);
    unsigned short* o = &agg[(long)node * D + lane * VPL];
    if constexpr (VPL == 4) {
        unsigned short ov[4] = {f2bf(acc[0] * inv), f2bf(acc[1] * inv),
                                f2bf(acc[2] * inv), f2bf(acc[3] * inv)};
        *(uint2*)o = *(const uint2*)ov;
    } else {
        unsigned short ov[2] = {f2bf(acc[0] * inv), f2bf(acc[1] * inv)};
        *(uint*)o = *(const uint*)ov;
    }
}

// ---------------------------------------------------------------- MFMA GEMM + BN stats
template<int K1, int K2>
__global__ __launch_bounds__(256) void mfma_gemm_kernel(
    const unsigned short* __restrict__ A1, const unsigned short* __restrict__ A2,
    const unsigned short* __restrict__ WT, const float* __restrict__ bias,
    unsigned short* __restrict__ Hout, float* __restrict__ s12) {
    constexpr int KT  = K1 + K2;
    constexpr int BK  = 64;
    constexpr int LDP = BK + 8;                 // 72 bf16: +16B row shift kills conflicts
    __shared__ unsigned short As[64 * LDP];     // 9.0 KB
    __shared__ unsigned short Bs[256 * LDP];    // 36 KB
    __shared__ float cs[256];                   // 1 KB
    __shared__ float cq[256];                   // 1 KB

    const int tid  = threadIdx.x;
    const int wave = tid >> 6;
    const int lane = tid & 63;
    const int m16  = lane & 15;
    const int quad = lane >> 4;
    const int rw   = (wave & 1) * 32;
    const int cw   = (wave >> 1) * 128;
    const int r0   = blockIdx.x * 64;

    if (tid < 256) { cs[tid] = 0.f; cq[tid] = 0.f; }

    f32x4 acc[2][8];
#pragma unroll
    for (int mt = 0; mt < 2; mt++)
#pragma unroll
        for (int nt = 0; nt < 8; nt++) acc[mt][nt] = (f32x4){0.f, 0.f, 0.f, 0.f};

    for (int k0 = 0; k0 < KT; k0 += BK) {
        const unsigned short* Ab;
        int pitch, kk;
        if (k0 < K1) { Ab = A1; pitch = K1; kk = k0; }
        else         { Ab = A2; pitch = K2; kk = k0 - K1; }
#pragma unroll
        for (int it = 0; it < 2; ++it) {
            int c = tid + it * 256;
            int row = c >> 3, ch = c & 7;
            int grow = min(r0 + row, N_NODES - 1);
            uint4 v = *(const uint4*)&Ab[(long)grow * pitch + kk + ch * 8];
            *(uint4*)&As[row * LDP + ch * 8] = v;
        }
#pragma unroll
        for (int it = 0; it < 8; ++it) {
            int c = tid + it * 256;
            int row = c >> 3, ch = c & 7;
            uint4 v = *(const uint4*)&WT[(long)row * KT + k0 + ch * 8];
            *(uint4*)&Bs[row * LDP + ch * 8] = v;
        }
        __syncthreads();
#pragma unroll
        for (int ks = 0; ks < 2; ++ks) {
            bf16x8 afrag[2], bfrag[8];
#pragma unroll
            for (int mt = 0; mt < 2; mt++)
                afrag[mt] = *(const bf16x8*)&As[(rw + mt * 16 + m16) * LDP + ks * 32 + quad * 8];
#pragma unroll
            for (int nt = 0; nt < 8; nt++)
                bfrag[nt] = *(const bf16x8*)&Bs[(cw + nt * 16 + m16) * LDP + ks * 32 + quad * 8];
#pragma unroll
            for (int mt = 0; mt < 2; mt++)
#pragma unroll
                for (int nt = 0; nt < 8; nt++)
                    acc[mt][nt] = __builtin_amdgcn_mfma_f32_16x16x32_bf16(
                        afrag[mt], bfrag[nt], acc[mt][nt], 0, 0, 0);
        }
        __syncthreads();
    }
    // epilogue: C/D layout col=lane&15, row=quad*4+reg; fused column stats
#pragma unroll
    for (int nt = 0; nt < 8; nt++) {
        int col = cw + nt * 16 + m16;
        float bv = bias[col];
        float s = 0.f, q = 0.f;
#pragma unroll
        for (int mt = 0; mt < 2; mt++) {
#pragma unroll
            for (int reg = 0; reg < 4; reg++) {
                int row = r0 + rw + mt * 16 + quad * 4 + reg;
                float v = acc[mt][nt][reg] + bv;
                if (row < N_NODES) {
                    Hout[(long)row * HID + col] = f2bf(v);
                    s += v;
                    q += v * v;
                }
            }
        }
        atomicAdd(&cs[col], s);
        atomicAdd(&cq[col], q);
    }
    __syncthreads();
    if (tid < 256) {
        atomicAdd(&s12[tid], cs[tid]);
        atomicAdd(&s12[HID + tid], cq[tid]);
    }
}

// ---------------------------------------------------------------- BN + ELU
template<bool OUT32>
__global__ void bn_elu_kernel(const unsigned short* __restrict__ h, const float* __restrict__ s12,
                              const float* __restrict__ g, const float* __restrict__ b,
                              void* __restrict__ out) {
    const int total4 = N_NODES * HID / 4;
    int i = blockIdx.x * blockDim.x + threadIdx.x;
    if (i >= total4) return;
    int c4 = (i % (HID / 4)) * 4;
    uint2 v = *(const uint2*)&h[(long)i * 4];
    float in[4] = {bf2f((unsigned short)(v.x & 0xFFFF)), bf2f((unsigned short)(v.x >> 16)),
                   bf2f((unsigned short)(v.y & 0xFFFF)), bf2f((unsigned short)(v.y >> 16))};
    float o[4];
#pragma unroll
    for (int j = 0; j < 4; j++) {
        int c = c4 + j;
        float mu  = s12[c] * (1.0f / N_NODES);
        float var = s12[HID + c] * (1.0f / N_NODES) - mu * mu;
        var = fmaxf(var, 0.f);
        float inv = rsqrtf(var + BN_EPS);
        float t = (in[j] - mu) * inv * g[c] + b[c];
        o[j] = t > 0.f ? t : expm1f(t);
    }
    if (OUT32) {
        float4 ov = {o[0], o[1], o[2], o[3]};
        *(float4*)&((float*)out)[(long)i * 4] = ov;
    } else {
        unsigned short ov[4] = {f2bf(o[0]), f2bf(o[1]), f2bf(o[2]), f2bf(o[3])};
        *(uint2*)&((unsigned short*)out)[(long)i * 4] = *(const uint2*)ov;
    }
}

// ---------------------------------------------------------------- launch
extern "C" void kernel_launch(void* const* d_in, const int* in_sizes, int n_in,
                              void* d_out, int out_size, void* d_ws, size_t ws_size,
                              hipStream_t stream) {
    const float* x   = (const float*)d_in[0];
    const int*   ei  = (const int*)d_in[1];
    const int*   src = ei;
    const int*   dst = ei + N_EDGES;
    const float* Wn[3] = {(const float*)d_in[2],  (const float*)d_in[7],  (const float*)d_in[12]};
    const float* bn[3] = {(const float*)d_in[3],  (const float*)d_in[8],  (const float*)d_in[13]};
    const float* Wr[3] = {(const float*)d_in[4],  (const float*)d_in[9],  (const float*)d_in[14]};
    const float* g [3] = {(const float*)d_in[5],  (const float*)d_in[10], (const float*)d_in[15]};
    const float* b [3] = {(const float*)d_in[6],  (const float*)d_in[11], (const float*)d_in[16]};
    float* out = (float*)d_out;

    const size_t BF = (size_t)N_NODES * HID * 2;   // 25.6 MB (bf16 N x 256)
    char* ws = (char*)d_ws;
    unsigned short* B0  = (unsigned short*)(ws);                  // agg bf16
    unsigned short* B1  = (unsigned short*)(ws + BF);             // gemm out bf16
    unsigned short* B2  = (unsigned short*)(ws + 2 * BF);         // activations bf16
    unsigned short* XB  = (unsigned short*)(ws + 3 * BF);         // x bf16 [N,128] 12.8 MB
    char* ws2 = ws + 3 * BF + (size_t)N_NODES * F_IN * 2;
    unsigned short* WT0 = (unsigned short*)(ws2);                 // [256][256]
    unsigned short* WT1 = (unsigned short*)(ws2 + 256 * 256 * 2);
    unsigned short* WT2 = (unsigned short*)(ws2 + 256 * 256 * 2 + 256 * 512 * 2);
    char* ws3 = ws2 + 256 * 256 * 2 + 2 * (256 * 512 * 2);
    int*   row_ptr = (int*)ws3;
    int*   cursor  = row_ptr + (N_NODES + 1);
    int*   deg_i   = cursor + N_NODES;
    int*   partial = deg_i + N_NODES;
    int*   csr_src = partial + SCAN_BLOCKS;
    float* s12     = (float*)(csr_src + N_EDGES);

    const int eb = (N_EDGES + 255) / 256;
    const int gather_blocks = (N_NODES + 3) / 4;
    const int elu_blocks = (N_NODES * HID / 4 + 255) / 256;
    const int gemm_blocks = (N_NODES + 63) / 64;

    // ---------------- one-time per call: CSR + bf16 weights/x
    hipMemsetAsync(deg_i, 0, N_NODES * sizeof(int), stream);
    hist_kernel<<<eb, 256, 0, stream>>>(dst, deg_i);
    scan1_kernel<<<SCAN_BLOCKS, 256, 0, stream>>>(deg_i, row_ptr, partial);
    scan2_kernel<<<1, 256, 0, stream>>>(partial);
    scan3_kernel<<<SCAN_BLOCKS, 256, 0, stream>>>(row_ptr, cursor, partial);
    fill_kernel<<<eb, 256, 0, stream>>>(src, dst, cursor, csr_src);
    cast_bf16_kernel<<<(N_NODES * F_IN / 4 + 255) / 256, 256, 0, stream>>>(x, XB, N_NODES * F_IN / 4);
    wt_kernel<<<256, 256, 0, stream>>>(Wn[0], Wr[0], F_IN, 2 * F_IN, WT0);
    wt_kernel<<<512, 256, 0, stream>>>(Wn[1], Wr[1], HID, 2 * HID, WT1);
    wt_kernel<<<512, 256, 0, stream>>>(Wn[2], Wr[2], HID, 2 * HID, WT2);

    // ---------------- layer 0: XB[N,128] -> act B2
    gather_mean_kernel<F_IN><<<gather_blocks, 256, 0, stream>>>(XB, row_ptr, csr_src, B0);
    hipMemsetAsync(s12, 0, 2 * HID * sizeof(float), stream);
    mfma_gemm_kernel<F_IN, F_IN><<<gemm_blocks, 256, 0, stream>>>(B0, XB, WT0, bn[0], B1, s12);
    bn_elu_kernel<false><<<elu_blocks, 256, 0, stream>>>(B1, s12, g[0], b[0], B2);

    // ---------------- layer 1: B2 -> act B2
    gather_mean_kernel<HID><<<gather_blocks, 256, 0, stream>>>(B2, row_ptr, csr_src, B0);
    hipMemsetAsync(s12, 0, 2 * HID * sizeof(float), stream);
    mfma_gemm_kernel<HID, HID><<<gemm_blocks, 256, 0, stream>>>(B0, B2, WT1, bn[1], B1, s12);
    bn_elu_kernel<false><<<elu_blocks, 256, 0, stream>>>(B1, s12, g[1], b[1], B2);

    // ---------------- layer 2: B2 -> out (fp32)
    gather_mean_kernel<HID><<<gather_blocks, 256, 0, stream>>>(B2, row_ptr, csr_src, B0);
    hipMemsetAsync(s12, 0, 2 * HID * sizeof(float), stream);
    mfma_gemm_kernel<HID, HID><<<gemm_blocks, 256, 0, stream>>>(B0, B2, WT2, bn[2], B1, s12);
    bn_elu_kernel<true><<<elu_blocks, 256, 0, stream>>>(B1, s12, g[2], b[2], out);
}